// Round 4
// baseline (378.466 us; speedup 1.0000x reference)
//
#include <hip/hip_runtime.h>
#include <hip/hip_bf16.h>

#define CDIM 64
#define KCODES 512
#define HWD 4096          // H*W
#define NPIX 131072       // B*H*W
#define NELEM 8388608     // B*C*H*W
// out layout (fp32 elements): [0]=loss, [1..1+NELEM)=quantized,
// then enc_idx(NPIX), perplexity(1), codes(NPIX)
#define OFF_Q 1
#define OFF_ENC (1 + NELEM)
#define OFF_PERP (1 + NELEM + NPIX)
#define OFF_CODES (1 + NELEM + NPIX + 1)

// numpy pairwise_sum for n=64 of separately-rounded squares of v[0..63]
__device__ __forceinline__ float np_pairwise_sq64(const float* v) {
    float r[8];
    #pragma unroll
    for (int j = 0; j < 8; ++j) r[j] = __fmul_rn(v[j], v[j]);
    #pragma unroll
    for (int i = 8; i < 64; i += 8) {
        #pragma unroll
        for (int j = 0; j < 8; ++j) r[j] = __fadd_rn(r[j], __fmul_rn(v[i + j], v[i + j]));
    }
    float s01 = __fadd_rn(r[0], r[1]);
    float s23 = __fadd_rn(r[2], r[3]);
    float s45 = __fadd_rn(r[4], r[5]);
    float s67 = __fadd_rn(r[6], r[7]);
    return __fadd_rn(__fadd_rn(s01, s23), __fadd_rn(s45, s67));
}

// ws float layout: [0]=loss_acc, [64..576)=counts, [576..1088)=ee
__global__ void ee_kernel(const float* __restrict__ e, float* __restrict__ ee) {
    int k = blockIdx.x * blockDim.x + threadIdx.x;
    if (k < KCODES) {
        float v[CDIM];
        #pragma unroll
        for (int c = 0; c < CDIM; ++c) v[c] = e[k * CDIM + c];
        ee[k] = np_pairwise_sq64(v);
    }
}

__launch_bounds__(256)
__global__ void vq_main(const float* __restrict__ in, const float* __restrict__ e,
                        const float* __restrict__ ee, float* __restrict__ loss_acc,
                        float* __restrict__ counts, float* __restrict__ out) {
    int p = blockIdx.x * 256 + threadIdx.x;
    int b = p >> 12;          // p / HWD
    int hw = p & (HWD - 1);

    const float* xin = in + (size_t)b * CDIM * HWD + hw;
    float x[CDIM];
    #pragma unroll
    for (int c = 0; c < CDIM; ++c) x[c] = xin[(size_t)c * HWD];

    // numpy: sum(flat*flat, axis=1) — rounded squares + pairwise-8 sum
    float xx = np_pairwise_sq64(x);

    float dmin = 3.4e38f;
    int idx = 0;
    for (int k = 0; k < KCODES; k += 4) {
        const float* e0 = e + (size_t)k * CDIM;
        // BLAS sgemm microkernel: sequential FMA chain over k per output elem
        float d0 = 0.f, d1 = 0.f, d2 = 0.f, d3 = 0.f;
        #pragma unroll
        for (int c = 0; c < CDIM; ++c) {
            float xc = x[c];
            d0 = __fmaf_rn(xc, e0[c], d0);
            d1 = __fmaf_rn(xc, e0[CDIM + c], d1);
            d2 = __fmaf_rn(xc, e0[2 * CDIM + c], d2);
            d3 = __fmaf_rn(xc, e0[3 * CDIM + c], d3);
        }
        // numpy: (xx + ee) rounded, then subtract exact 2*dot, rounded
        float dd0 = __fsub_rn(__fadd_rn(xx, ee[k + 0]), __fmul_rn(2.f, d0));
        float dd1 = __fsub_rn(__fadd_rn(xx, ee[k + 1]), __fmul_rn(2.f, d1));
        float dd2 = __fsub_rn(__fadd_rn(xx, ee[k + 2]), __fmul_rn(2.f, d2));
        float dd3 = __fsub_rn(__fadd_rn(xx, ee[k + 3]), __fmul_rn(2.f, d3));
        if (dd0 < dmin) { dmin = dd0; idx = k + 0; }
        if (dd1 < dmin) { dmin = dd1; idx = k + 1; }
        if (dd2 < dmin) { dmin = dd2; idx = k + 2; }
        if (dd3 < dmin) { dmin = dd3; idx = k + 3; }
    }

    // quantized output (fp32) + latent-loss partial
    const float4* eq = reinterpret_cast<const float4*>(e + (size_t)idx * CDIM);
    float* outq = out + OFF_Q + (size_t)b * CDIM * HWD + hw;
    float lsum = 0.f;
    #pragma unroll
    for (int j = 0; j < 16; ++j) {
        float4 q = eq[j];
        int c = 4 * j;
        outq[(size_t)(c + 0) * HWD] = q.x;
        outq[(size_t)(c + 1) * HWD] = q.y;
        outq[(size_t)(c + 2) * HWD] = q.z;
        outq[(size_t)(c + 3) * HWD] = q.w;
        float t0 = q.x - x[c + 0];
        float t1 = q.y - x[c + 1];
        float t2 = q.z - x[c + 2];
        float t3 = q.w - x[c + 3];
        lsum = fmaf(t0, t0, lsum);
        lsum = fmaf(t1, t1, lsum);
        lsum = fmaf(t2, t2, lsum);
        lsum = fmaf(t3, t3, lsum);
    }

    float fidx = (float)idx;
    out[OFF_ENC + p] = fidx;
    out[OFF_CODES + p] = fidx;

    atomicAdd(&counts[idx], 1.0f);

    // wave-reduce loss partial (wave = 64)
    #pragma unroll
    for (int off = 32; off > 0; off >>= 1) lsum += __shfl_down(lsum, off, 64);
    if ((threadIdx.x & 63) == 0) atomicAdd(loss_acc, lsum);
}

__global__ void finalize_kernel(const float* __restrict__ loss_acc,
                                const float* __restrict__ counts,
                                float* __restrict__ out) {
    __shared__ float red[8];
    int t = threadIdx.x;  // 512 threads
    float pr = counts[t] * (1.0f / (float)NPIX);
    float term = pr * logf(pr + 1e-10f);
    #pragma unroll
    for (int off = 32; off > 0; off >>= 1) term += __shfl_down(term, off, 64);
    if ((t & 63) == 0) red[t >> 6] = term;
    __syncthreads();
    if (t == 0) {
        float s = 0.f;
        #pragma unroll
        for (int i = 0; i < 8; ++i) s += red[i];
        out[OFF_PERP] = expf(-s);
        out[0] = 0.25f * loss_acc[0] * (1.0f / (float)NELEM);
    }
}

extern "C" void kernel_launch(void* const* d_in, const int* in_sizes, int n_in,
                              void* d_out, int out_size, void* d_ws, size_t ws_size,
                              hipStream_t stream) {
    const float* in = (const float*)d_in[0];
    const float* e = (const float*)d_in[1];
    float* out = (float*)d_out;
    float* wsf = (float*)d_ws;
    float* loss_acc = wsf + 0;
    float* counts = wsf + 64;
    float* ee = wsf + 576;

    hipMemsetAsync(d_ws, 0, 2304, stream);  // loss_acc + counts
    ee_kernel<<<1, 512, 0, stream>>>(e, ee);
    vq_main<<<NPIX / 256, 256, 0, stream>>>(in, e, ee, loss_acc, counts, out);
    finalize_kernel<<<1, 512, 0, stream>>>(loss_acc, counts, out);
}

// Round 5
// 377.057 us; speedup vs baseline: 1.0037x; 1.0037x over previous
//
#include <hip/hip_runtime.h>
#include <hip/hip_bf16.h>

#define CDIM 64
#define KCODES 512
#define HWD 4096          // H*W
#define NPIX 131072       // B*H*W
#define NELEM 8388608     // B*C*H*W
// out layout (fp32 elements): [0]=loss, [1..1+NELEM)=quantized,
// then enc_idx(NPIX), perplexity(1), codes(NPIX)
#define OFF_Q 1
#define OFF_ENC (1 + NELEM)
#define OFF_PERP (1 + NELEM + NPIX)
#define OFF_CODES (1 + NELEM + NPIX + 1)

// numpy pairwise_sum for n=64 of separately-rounded squares of v[0..63]
__device__ __forceinline__ float np_pairwise_sq64(const float* v) {
    float r[8];
    #pragma unroll
    for (int j = 0; j < 8; ++j) r[j] = __fmul_rn(v[j], v[j]);
    #pragma unroll
    for (int i = 8; i < 64; i += 8) {
        #pragma unroll
        for (int j = 0; j < 8; ++j) r[j] = __fadd_rn(r[j], __fmul_rn(v[i + j], v[i + j]));
    }
    float s01 = __fadd_rn(r[0], r[1]);
    float s23 = __fadd_rn(r[2], r[3]);
    float s45 = __fadd_rn(r[4], r[5]);
    float s67 = __fadd_rn(r[6], r[7]);
    return __fadd_rn(__fadd_rn(s01, s23), __fadd_rn(s45, s67));
}

// ws float layout: [0]=loss_acc, [64..576)=counts, [576..1088)=ee
__global__ void ee_kernel(const float* __restrict__ e, float* __restrict__ ee) {
    int k = blockIdx.x * blockDim.x + threadIdx.x;
    if (k < KCODES) {
        float v[CDIM];
        #pragma unroll
        for (int c = 0; c < CDIM; ++c) v[c] = e[k * CDIM + c];
        ee[k] = np_pairwise_sq64(v);
    }
}

// __launch_bounds__(256, 1): 1 wave/EU min -> full VGPR budget. Round-4 run
// showed VGPR_Count=44 (x[64] spilled, VALUBusy 40%). Grid is 2 blocks/CU
// (8 waves/CU) regardless, so high VGPR use costs no occupancy.
__launch_bounds__(256, 1)
__global__ void vq_main(const float* __restrict__ in, const float* __restrict__ e,
                        const float* __restrict__ ee, float* __restrict__ loss_acc,
                        float* __restrict__ counts, float* __restrict__ out) {
    int p = blockIdx.x * 256 + threadIdx.x;
    int b = p >> 12;          // p / HWD
    int hw = p & (HWD - 1);

    const float* xin = in + (size_t)b * CDIM * HWD + hw;
    float x[CDIM];
    #pragma unroll
    for (int c = 0; c < CDIM; ++c) x[c] = xin[(size_t)c * HWD];

    // numpy: sum(flat*flat, axis=1) — rounded squares + pairwise-8 sum
    float xx = np_pairwise_sq64(x);

    float dmin = 3.4e38f;
    int idx = 0;
    for (int k = 0; k < KCODES; k += 4) {
        const float* e0 = e + (size_t)k * CDIM;
        // BLAS sgemm microkernel: sequential FMA chain over k per output elem
        float d0 = 0.f, d1 = 0.f, d2 = 0.f, d3 = 0.f;
        #pragma unroll
        for (int c = 0; c < CDIM; ++c) {
            float xc = x[c];
            d0 = __fmaf_rn(xc, e0[c], d0);
            d1 = __fmaf_rn(xc, e0[CDIM + c], d1);
            d2 = __fmaf_rn(xc, e0[2 * CDIM + c], d2);
            d3 = __fmaf_rn(xc, e0[3 * CDIM + c], d3);
        }
        // numpy: (xx + ee) rounded, then subtract exact 2*dot, rounded
        float dd0 = __fsub_rn(__fadd_rn(xx, ee[k + 0]), __fmul_rn(2.f, d0));
        float dd1 = __fsub_rn(__fadd_rn(xx, ee[k + 1]), __fmul_rn(2.f, d1));
        float dd2 = __fsub_rn(__fadd_rn(xx, ee[k + 2]), __fmul_rn(2.f, d2));
        float dd3 = __fsub_rn(__fadd_rn(xx, ee[k + 3]), __fmul_rn(2.f, d3));
        if (dd0 < dmin) { dmin = dd0; idx = k + 0; }
        if (dd1 < dmin) { dmin = dd1; idx = k + 1; }
        if (dd2 < dmin) { dmin = dd2; idx = k + 2; }
        if (dd3 < dmin) { dmin = dd3; idx = k + 3; }
    }

    // quantized output (fp32) + latent-loss partial
    const float4* eq = reinterpret_cast<const float4*>(e + (size_t)idx * CDIM);
    float* outq = out + OFF_Q + (size_t)b * CDIM * HWD + hw;
    float lsum = 0.f;
    #pragma unroll
    for (int j = 0; j < 16; ++j) {
        float4 q = eq[j];
        int c = 4 * j;
        outq[(size_t)(c + 0) * HWD] = q.x;
        outq[(size_t)(c + 1) * HWD] = q.y;
        outq[(size_t)(c + 2) * HWD] = q.z;
        outq[(size_t)(c + 3) * HWD] = q.w;
        float t0 = q.x - x[c + 0];
        float t1 = q.y - x[c + 1];
        float t2 = q.z - x[c + 2];
        float t3 = q.w - x[c + 3];
        lsum = fmaf(t0, t0, lsum);
        lsum = fmaf(t1, t1, lsum);
        lsum = fmaf(t2, t2, lsum);
        lsum = fmaf(t3, t3, lsum);
    }

    float fidx = (float)idx;
    out[OFF_ENC + p] = fidx;
    out[OFF_CODES + p] = fidx;

    atomicAdd(&counts[idx], 1.0f);

    // wave-reduce loss partial (wave = 64)
    #pragma unroll
    for (int off = 32; off > 0; off >>= 1) lsum += __shfl_down(lsum, off, 64);
    if ((threadIdx.x & 63) == 0) atomicAdd(loss_acc, lsum);
}

__global__ void finalize_kernel(const float* __restrict__ loss_acc,
                                const float* __restrict__ counts,
                                float* __restrict__ out) {
    __shared__ float red[8];
    int t = threadIdx.x;  // 512 threads
    float pr = counts[t] * (1.0f / (float)NPIX);
    float term = pr * logf(pr + 1e-10f);
    #pragma unroll
    for (int off = 32; off > 0; off >>= 1) term += __shfl_down(term, off, 64);
    if ((t & 63) == 0) red[t >> 6] = term;
    __syncthreads();
    if (t == 0) {
        float s = 0.f;
        #pragma unroll
        for (int i = 0; i < 8; ++i) s += red[i];
        out[OFF_PERP] = expf(-s);
        out[0] = 0.25f * loss_acc[0] * (1.0f / (float)NELEM);
    }
}

extern "C" void kernel_launch(void* const* d_in, const int* in_sizes, int n_in,
                              void* d_out, int out_size, void* d_ws, size_t ws_size,
                              hipStream_t stream) {
    const float* in = (const float*)d_in[0];
    const float* e = (const float*)d_in[1];
    float* out = (float*)d_out;
    float* wsf = (float*)d_ws;
    float* loss_acc = wsf + 0;
    float* counts = wsf + 64;
    float* ee = wsf + 576;

    hipMemsetAsync(d_ws, 0, 2304, stream);  // loss_acc + counts
    ee_kernel<<<1, 512, 0, stream>>>(e, ee);
    vq_main<<<NPIX / 256, 256, 0, stream>>>(in, e, ee, loss_acc, counts, out);
    finalize_kernel<<<1, 512, 0, stream>>>(loss_acc, counts, out);
}